// Round 6
// baseline (783.310 us; speedup 1.0000x reference)
//
#include <hip/hip_runtime.h>

#define N_NODES 100000
#define N_EDGES 1600000
#define D_FEAT  64

#define BUCK_SHIFT 7
#define BUCK_NODES 128                                   // nodes per bucket
#define NBUCK ((N_NODES + BUCK_NODES - 1) / BUCK_NODES)  // 782
#define CUR_PAD 16                                       // one cache line per cursor

#define BIN_BLK 256
#define BIN_EPT 16
#define BIN_CHUNK (BIN_BLK * BIN_EPT)                    // 4096 edges per block
#define NCHUNK ((N_EDGES + BIN_CHUNK - 1) / BIN_CHUNK)   // 391

typedef float vf4 __attribute__((ext_vector_type(4)));   // NT-store-able float4

// ---------------------------------------------------------------------------
// Workspace layout:
//   bcnt  : int[NBUCK]            bucket histogram
//   bbase : int[NBUCK+1]          exclusive scan (bucket segment starts)
//   bcur  : int[NBUCK*CUR_PAD]    append cursors (line-padded)
//   ep    : int2[N_EDGES]         packed payload (.x = ld<<24|src, .y = w bits)
// ---------------------------------------------------------------------------
#define OFF_BCNT  0
#define OFF_BBASE (OFF_BCNT + NBUCK * 4)
#define OFF_BCUR  (OFF_BBASE + (NBUCK + 1) * 4)
#define OFF_EP    (((OFF_BCUR + NBUCK * CUR_PAD * 4) + 255) & ~255)
#define WS_NEEDED (size_t)(OFF_EP + (size_t)N_EDGES * 8)

__global__ void k_bhist(const int* __restrict__ dst, int* __restrict__ bcnt) {
    __shared__ int h[NBUCK];
    for (int i = threadIdx.x; i < NBUCK; i += blockDim.x) h[i] = 0;
    __syncthreads();
    const int stride = gridDim.x * blockDim.x;
    for (int e = blockIdx.x * blockDim.x + threadIdx.x; e < N_EDGES; e += stride)
        atomicAdd(&h[__builtin_nontemporal_load(dst + e) >> BUCK_SHIFT], 1);
    __syncthreads();
    for (int i = threadIdx.x; i < NBUCK; i += blockDim.x)
        if (h[i]) atomicAdd(&bcnt[i], h[i]);
}

// Exclusive scan of NBUCK (=782) counts in one 1024-thread block.
__global__ void k_bscan(const int* __restrict__ bcnt, int* __restrict__ bbase,
                        int* __restrict__ bcur) {
    __shared__ int tmp[1024];
    const int t = threadIdx.x;
    int v = (t < NBUCK) ? bcnt[t] : 0;
    tmp[t] = v;
    __syncthreads();
    for (int off = 1; off < 1024; off <<= 1) {
        int x = (t >= off) ? tmp[t - off] : 0;
        __syncthreads();
        tmp[t] += x;
        __syncthreads();
    }
    if (t < NBUCK) {
        int ex = tmp[t] - v;
        bbase[t] = ex;
        bcur[t * CUR_PAD] = ex;
    }
    if (t == 0) bbase[NBUCK] = N_EDGES;
}

// One block per 4096-edge chunk: LDS rank-assign per bucket, one global cursor
// reservation per (chunk,bucket), then payload writes. Same-bucket writes of a
// chunk hit consecutive slots from one CU within a short window -> the 64B
// lines fill in L2 before eviction (write-combining the binning pass).
__global__ __launch_bounds__(BIN_BLK) void k_bin(const int* __restrict__ src,
                                                 const int* __restrict__ dst,
                                                 const float* __restrict__ weight,
                                                 int* __restrict__ bcur,
                                                 int2* __restrict__ ep) {
    __shared__ int lcnt[NBUCK];
    __shared__ int lbase[NBUCK];
    const int t = threadIdx.x;
    const int e0 = blockIdx.x * BIN_CHUNK;
    for (int i = t; i < NBUCK; i += BIN_BLK) lcnt[i] = 0;
    __syncthreads();
    int bk[BIN_EPT], rk[BIN_EPT], xk[BIN_EPT], wk[BIN_EPT];
#pragma unroll
    for (int k = 0; k < BIN_EPT; ++k) {
        const int e = e0 + t + k * BIN_BLK;   // coalesced
        bk[k] = -1;
        if (e < N_EDGES) {
            int v = __builtin_nontemporal_load(dst + e);
            int s = __builtin_nontemporal_load(src + e);
            wk[k] = __builtin_nontemporal_load((const int*)weight + e);
            int b = v >> BUCK_SHIFT;
            bk[k] = b;
            xk[k] = ((v & (BUCK_NODES - 1)) << 24) | s;   // src < 2^17
            rk[k] = atomicAdd(&lcnt[b], 1);
        }
    }
    __syncthreads();
    for (int i = t; i < NBUCK; i += BIN_BLK) {
        int c = lcnt[i];
        if (c) lbase[i] = atomicAdd(&bcur[i * CUR_PAD], c);
    }
    __syncthreads();
#pragma unroll
    for (int k = 0; k < BIN_EPT; ++k)
        if (bk[k] >= 0) ep[lbase[bk[k]] + rk[k]] = make_int2(xk[k], wk[k]);
}

// One block per bucket: 32 KB LDS fp32 accumulator (4 blocks/CU -> 16 waves),
// wave-cooperative payload loads, 8-way unrolled feat-row gather, ds_add_f32.
__global__ __launch_bounds__(256) void k_bgather(const float* __restrict__ feat,
                                                 const float* __restrict__ bias,
                                                 const int* __restrict__ bbase,
                                                 const int2* __restrict__ ep,
                                                 float* __restrict__ out) {
    __shared__ float acc[BUCK_NODES * D_FEAT];   // 32 KB
    const int t = threadIdx.x;
    const int lane = t & 63;
    const int wid = t >> 6;
    const int b = blockIdx.x;

    vf4* a4 = (vf4*)acc;
    for (int i = t; i < BUCK_NODES * D_FEAT / 4; i += 256)
        a4[i] = (vf4){0.f, 0.f, 0.f, 0.f};
    __syncthreads();

    const int g0 = bbase[b];
    const int g1 = bbase[b + 1];
    const long long* epq = (const long long*)ep;

#define ACC_ADD(X, W, F)                                                      \
    __hip_atomic_fetch_add(&acc[((unsigned)(X) >> 24) * D_FEAT + lane],        \
                           (W) * (F), __ATOMIC_RELAXED,                        \
                           __HIP_MEMORY_SCOPE_WORKGROUP)

    for (int base = g0 + wid * 64; base < g1; base += 256) {
        const int n = min(64, g1 - base);
        long long q = 0;
        if (base + lane < g1) q = __builtin_nontemporal_load(epq + base + lane);
        const int px = (int)(q & 0xffffffffLL);
        const int pw = (int)(q >> 32);
        int j = 0;
        for (; j + 8 <= n; j += 8) {
            int x0 = __shfl(px, j + 0); float w0 = __int_as_float(__shfl(pw, j + 0));
            int x1 = __shfl(px, j + 1); float w1 = __int_as_float(__shfl(pw, j + 1));
            int x2 = __shfl(px, j + 2); float w2 = __int_as_float(__shfl(pw, j + 2));
            int x3 = __shfl(px, j + 3); float w3 = __int_as_float(__shfl(pw, j + 3));
            int x4 = __shfl(px, j + 4); float w4 = __int_as_float(__shfl(pw, j + 4));
            int x5 = __shfl(px, j + 5); float w5 = __int_as_float(__shfl(pw, j + 5));
            int x6 = __shfl(px, j + 6); float w6 = __int_as_float(__shfl(pw, j + 6));
            int x7 = __shfl(px, j + 7); float w7 = __int_as_float(__shfl(pw, j + 7));
            float f0 = feat[(x0 & 0xFFFFFF) * D_FEAT + lane];
            float f1 = feat[(x1 & 0xFFFFFF) * D_FEAT + lane];
            float f2 = feat[(x2 & 0xFFFFFF) * D_FEAT + lane];
            float f3 = feat[(x3 & 0xFFFFFF) * D_FEAT + lane];
            float f4 = feat[(x4 & 0xFFFFFF) * D_FEAT + lane];
            float f5 = feat[(x5 & 0xFFFFFF) * D_FEAT + lane];
            float f6 = feat[(x6 & 0xFFFFFF) * D_FEAT + lane];
            float f7 = feat[(x7 & 0xFFFFFF) * D_FEAT + lane];
            ACC_ADD(x0, w0, f0); ACC_ADD(x1, w1, f1);
            ACC_ADD(x2, w2, f2); ACC_ADD(x3, w3, f3);
            ACC_ADD(x4, w4, f4); ACC_ADD(x5, w5, f5);
            ACC_ADD(x6, w6, f6); ACC_ADD(x7, w7, f7);
        }
        for (; j < n; ++j) {
            int   x = __shfl(px, j);
            float w = __int_as_float(__shfl(pw, j));
            float f = feat[(x & 0xFFFFFF) * D_FEAT + lane];
            ACC_ADD(x, w, f);
        }
    }
#undef ACC_ADD
    __syncthreads();

    // bias-fused float4 output: flat float4 index f -> row f>>4, col4 f&15.
    // stride 256 is 0 mod 16, so col4 (and thus bias4) is constant per thread.
    const vf4 b4 = ((const vf4*)bias)[t & 15];
    const int vbase = b * BUCK_NODES;
    for (int f = t; f < BUCK_NODES * (D_FEAT / 4); f += 256) {
        int row = f >> 4;
        if (vbase + row < N_NODES) {
            vf4 a = a4[f];
            a += b4;
            __builtin_nontemporal_store(a, (vf4*)&out[(size_t)(vbase + row) * D_FEAT] + (f & 15));
        }
    }
}

// ---------------- fallback (ws too small): direct atomic path ---------------
__global__ void init_out_kernel(const float* __restrict__ bias,
                                float* __restrict__ out) {
    int i = blockIdx.x * blockDim.x + threadIdx.x;
    if (i < N_NODES * D_FEAT) out[i] = bias[i & (D_FEAT - 1)];
}

__global__ void edge_scatter_kernel(const float* __restrict__ feat,
                                    const float* __restrict__ weight,
                                    const int* __restrict__ src,
                                    const int* __restrict__ dst,
                                    float* __restrict__ out) {
    int e = blockIdx.x * 4 + (threadIdx.x >> 6);
    int lane = threadIdx.x & 63;
    if (e < N_EDGES) {
        atomicAdd(&out[dst[e] * D_FEAT + lane], weight[e] * feat[src[e] * D_FEAT + lane]);
    }
}

extern "C" void kernel_launch(void* const* d_in, const int* in_sizes, int n_in,
                              void* d_out, int out_size, void* d_ws, size_t ws_size,
                              hipStream_t stream) {
    const float* feat   = (const float*)d_in[0];
    const float* weight = (const float*)d_in[1];
    const float* bias   = (const float*)d_in[2];
    const int*   src    = (const int*)d_in[3];
    const int*   dst    = (const int*)d_in[4];
    float* out = (float*)d_out;

    if (ws_size < WS_NEEDED) {
        int total = N_NODES * D_FEAT;
        init_out_kernel<<<(total + 255) / 256, 256, 0, stream>>>(bias, out);
        edge_scatter_kernel<<<(N_EDGES + 3) / 4, 256, 0, stream>>>(feat, weight, src, dst, out);
        return;
    }

    char* ws = (char*)d_ws;
    int*  bcnt  = (int*)(ws + OFF_BCNT);
    int*  bbase = (int*)(ws + OFF_BBASE);
    int*  bcur  = (int*)(ws + OFF_BCUR);
    int2* ep    = (int2*)(ws + OFF_EP);

    (void)hipMemsetAsync(bcnt, 0, NBUCK * sizeof(int), stream);
    k_bhist<<<256, 256, 0, stream>>>(dst, bcnt);
    k_bscan<<<1, 1024, 0, stream>>>(bcnt, bbase, bcur);
    k_bin<<<NCHUNK, BIN_BLK, 0, stream>>>(src, dst, weight, bcur, ep);
    k_bgather<<<NBUCK, 256, 0, stream>>>(feat, bias, bbase, ep, out);
}